// Round 3
// baseline (203.185 us; speedup 1.0000x reference)
//
#include <hip/hip_runtime.h>
#include <math.h>

// NeRF ray integration, v7 = barrier-free, persistent-shaped pipeline.
//  Post-mortem v6: LDS staging of color was ~neutral (gain matched K2-fusion
//  alone) -> coalescing wasn't the limiter. New theory: block lifecycle.
//  v6 ran 8192 one-shot blocks, each load -> __syncthreads -> compute; every
//  wave stalls at the barrier on the slowest HBM load and blocks churn.
//  v7:
//   - NO __syncthreads: color staging is wave-local (each wave stages its own
//     2 rays / 3KB; DS pipe is in-order per wave, so write->read needs no
//     barrier).
//   - 2048 blocks x 4 ray-tiles each (exactly 8 resident blocks/CU, no churn),
//     2-deep software pipeline: tile r+1's 5 global loads issue before tile
//     r's compute -> each wave always has a full tile of loads in flight.
//  Same verified math core: 2 rays/wave, 4 samples/lane, shfl_up scan,
//  5 exp, shfl_xor reduction. Same output layout.

#define NRAYS 65536
#define S 128
#define RAYS_PER_TILE 8                       // 4 waves * 2 rays
#define TILES 4
#define BLOCKS (NRAYS / (RAYS_PER_TILE * TILES))   // 2048

typedef float __attribute__((ext_vector_type(4))) fvec4;

struct TileRegs { fvec4 tv, sv, g0, g1, g2; };

__device__ __forceinline__ TileRegs load_tile(
    const float* __restrict__ t, const float* __restrict__ sigma,
    const float* __restrict__ color, long tileIdx, int seg, int seglane,
    int wave, int lane)
{
    TileRegs r;
    const long ray   = tileIdx * RAYS_PER_TILE + seg;
    const long sbase = ray * S + 4 * seglane;
    r.tv = __builtin_nontemporal_load((const fvec4*)(t + sbase));
    r.sv = __builtin_nontemporal_load((const fvec4*)(sigma + sbase));
    // wave-local coalesced color: this wave's 2 rays = 768 floats = 192 float4
    const fvec4* gc = (const fvec4*)(color +
        (tileIdx * RAYS_PER_TILE + 2 * wave) * (long)(S * 3));
    r.g0 = __builtin_nontemporal_load(gc + lane);
    r.g1 = __builtin_nontemporal_load(gc + lane + 64);
    r.g2 = __builtin_nontemporal_load(gc + lane + 128);
    return r;
}

__device__ __forceinline__ void compute_tile(
    const TileRegs& R, fvec4* __restrict__ lds_w, long tileIdx, int seg,
    int seglane, int lane,
    float* __restrict__ out_color, float* __restrict__ out_depth,
    float* __restrict__ out_wi, float* __restrict__ out_t)
{
    const long ray   = tileIdx * RAYS_PER_TILE + seg;
    const long sbase = ray * S + 4 * seglane;

    // fused t-copy: tv already in registers
    __builtin_nontemporal_store(R.tv, (fvec4*)(out_t + sbase));

    // wave-local color stage (no barrier: DS pipe in-order within a wave)
    lds_w[lane]       = R.g0;
    lds_w[lane + 64]  = R.g1;
    lds_w[lane + 128] = R.g2;
    // per-lane fragment: ray (lane>>5) of this wave's 2, samples 4*seglane..+3
    const int cidx = (lane >> 5) * 96 + 3 * seglane;
    const fvec4 c0 = lds_w[cidx + 0];
    const fvec4 c1 = lds_w[cidx + 1];
    const fvec4 c2 = lds_w[cidx + 2];

    // dt
    const float t_next = __shfl_down(R.tv.x, 1, 32);
    const float dt0 = R.tv.y - R.tv.x;
    const float dt1 = R.tv.z - R.tv.y;
    const float dt2 = R.tv.w - R.tv.z;
    const float dt3 = (seglane == 31) ? 0.0f : (t_next - R.tv.w);

    // per-lane prefix of sigma*dt
    const float p0  = R.sv.x * dt0;
    const float p1  = p0 + R.sv.y * dt1;
    const float p2  = p1 + R.sv.z * dt2;
    const float tot = p2 + R.sv.w * dt3;

    // 32-lane inclusive scan
    float scan = tot;
    #pragma unroll
    for (int off = 1; off < 32; off <<= 1) {
        const float v = __shfl_up(scan, off, 32);
        if (seglane >= off) scan += v;
    }
    const float excl = scan - tot;

    // transmittance & weights
    const float E0 = __expf(-excl);
    const float e0 = __expf(-(excl + p0));
    const float e1 = __expf(-(excl + p1));
    const float e2 = __expf(-(excl + p2));
    const float e3 = __expf(-scan);
    const float wi0 = E0 - e0;
    const float wi1 = e0 - e1;
    const float wi2 = e1 - e2;
    const float wi3 = e2 - e3;

    fvec4 wiv; wiv.x = wi0; wiv.y = wi1; wiv.z = wi2; wiv.w = wi3;
    __builtin_nontemporal_store(wiv, (fvec4*)(out_wi + sbase));

    // weighted color + depth
    // sample 4l+0: c0.x c0.y c0.z | 4l+1: c0.w c1.x c1.y
    // sample 4l+2: c1.z c1.w c2.x | 4l+3: c2.y c2.z c2.w
    float r = wi0 * c0.x + wi1 * c0.w + wi2 * c1.z + wi3 * c2.y;
    float g = wi0 * c0.y + wi1 * c1.x + wi2 * c1.w + wi3 * c2.z;
    float b = wi0 * c0.z + wi1 * c1.y + wi2 * c2.x + wi3 * c2.w;
    float d = wi0 * R.tv.x + wi1 * R.tv.y + wi2 * R.tv.z + wi3 * R.tv.w;

    #pragma unroll
    for (int off = 16; off >= 1; off >>= 1) {
        r += __shfl_xor(r, off, 32);
        g += __shfl_xor(g, off, 32);
        b += __shfl_xor(b, off, 32);
        d += __shfl_xor(d, off, 32);
    }

    if (seglane == 0) {
        out_color[ray * 3 + 0] = r;
        out_color[ray * 3 + 1] = g;
        out_color[ray * 3 + 2] = b;
        out_depth[ray] = d;
    }
}

__global__ __launch_bounds__(256) void nerf_fused_kernel(
    const float* __restrict__ t,
    const float* __restrict__ sigma,
    const float* __restrict__ color,
    float* __restrict__ out_color,   // [N,3]
    float* __restrict__ out_depth,   // [N,1]
    float* __restrict__ out_wi,      // [N,S]
    float* __restrict__ out_t)       // [N,S]
{
    // per-wave color staging: 4 waves * 192 float4 = 12 KB
    __shared__ fvec4 lds_c[4][192];

    const int tid     = threadIdx.x;
    const int lane    = tid & 63;
    const int seglane = tid & 31;
    const int wave    = tid >> 6;     // 0..3
    const int seg     = tid >> 5;     // 0..7, ray within tile

    fvec4* lds_w = lds_c[wave];
    const long base = (long)blockIdx.x * TILES;

    TileRegs cur = load_tile(t, sigma, color, base, seg, seglane, wave, lane);
    #pragma unroll
    for (int r = 0; r < TILES; ++r) {
        TileRegs nxt;
        if (r + 1 < TILES)
            nxt = load_tile(t, sigma, color, base + r + 1, seg, seglane, wave, lane);
        compute_tile(cur, lds_w, base + r, seg, seglane, lane,
                     out_color, out_depth, out_wi, out_t);
        cur = nxt;
    }
}

extern "C" void kernel_launch(void* const* d_in, const int* in_sizes, int n_in,
                              void* d_out, int out_size, void* d_ws, size_t ws_size,
                              hipStream_t stream) {
    const float* t     = (const float*)d_in[0];
    const float* sigma = (const float*)d_in[1];
    const float* color = (const float*)d_in[2];

    float* out = (float*)d_out;
    float* out_color = out;                         // N*3
    float* out_depth = out_color + (long)NRAYS * 3; // N
    float* out_wi    = out_depth + NRAYS;           // N*S
    float* out_t     = out_wi + (long)NRAYS * S;    // N*S

    nerf_fused_kernel<<<BLOCKS, 256, 0, stream>>>(
        t, sigma, color, out_color, out_depth, out_wi, out_t);
}

// Round 4
// 199.866 us; speedup vs baseline: 1.0166x; 1.0166x over previous
//
#include <hip/hip_runtime.h>
#include <math.h>

// NeRF ray integration, v8 = v6 structure, barrier removed (single isolated
// change). Post-mortem v7: persistent 2-deep pipeline regressed (+5.4us,
// +40 VGPR of in-flight TileRegs); wave-local staging itself was verified
// correct there. v8 keeps v6's 8192 one-shot blocks and minimal register
// footprint, but stages color per-wave (3KB each, DS pipe is in-order within
// a wave -> no __syncthreads anywhere). Theory: v6's barrier coupled all 4
// waves to the block's slowest HBM load; if that coupling was real this is
// worth a few us, if neutral the kernel is at its memory floor (235.7 MB
// @ ~6.3 TB/s ~= 37us + launch/tail) and the rest of dur_us is harness-fixed.

#define NRAYS 65536
#define S 128
#define RAYS_PER_BLOCK 8   // 4 waves * 2 rays

typedef float __attribute__((ext_vector_type(4))) fvec4;

__global__ __launch_bounds__(256) void nerf_fused_kernel(
    const float* __restrict__ t,
    const float* __restrict__ sigma,
    const float* __restrict__ color,
    float* __restrict__ out_color,   // [N,3]
    float* __restrict__ out_depth,   // [N,1]
    float* __restrict__ out_wi,      // [N,S]
    float* __restrict__ out_t)       // [N,S]
{
    // per-wave color staging: 4 waves * 192 float4 = 12 KB total
    __shared__ fvec4 lds_c[4][192];

    const int tid     = threadIdx.x;
    const int lane    = tid & 63;
    const int seglane = tid & 31;
    const int wave    = tid >> 6;     // 0..3
    const int seg     = tid >> 5;     // 0..7, ray within block
    const long ray    = (long)blockIdx.x * RAYS_PER_BLOCK + seg;
    const long sbase  = ray * S + 4 * seglane;

    // ---- issue all global loads up front ----
    const fvec4 tv = __builtin_nontemporal_load((const fvec4*)(t + sbase));
    const fvec4 sv = __builtin_nontemporal_load((const fvec4*)(sigma + sbase));
    // wave-local coalesced color: this wave's 2 rays = 768 floats = 192 float4
    const fvec4* gc = (const fvec4*)(color +
        ((long)blockIdx.x * RAYS_PER_BLOCK + 2 * wave) * (long)(S * 3));
    const fvec4 g0 = __builtin_nontemporal_load(gc + lane);
    const fvec4 g1 = __builtin_nontemporal_load(gc + lane + 64);
    const fvec4 g2 = __builtin_nontemporal_load(gc + lane + 128);

    // fused t-copy: tv already in registers
    __builtin_nontemporal_store(tv, (fvec4*)(out_t + sbase));

    // wave-local color stage (no barrier: DS pipe in-order within a wave)
    fvec4* lds_w = lds_c[wave];
    lds_w[lane]       = g0;
    lds_w[lane + 64]  = g1;
    lds_w[lane + 128] = g2;
    // per-lane fragment: ray (lane>>5) of this wave's 2, samples 4*seglane..+3
    const int cidx = (lane >> 5) * 96 + 3 * seglane;
    const fvec4 c0 = lds_w[cidx + 0];
    const fvec4 c1 = lds_w[cidx + 1];
    const fvec4 c2 = lds_w[cidx + 2];

    // ---- dt ----
    const float t_next = __shfl_down(tv.x, 1, 32);
    const float dt0 = tv.y - tv.x;
    const float dt1 = tv.z - tv.y;
    const float dt2 = tv.w - tv.z;
    const float dt3 = (seglane == 31) ? 0.0f : (t_next - tv.w);

    // ---- per-lane prefix of sigma*dt ----
    const float p0  = sv.x * dt0;
    const float p1  = p0 + sv.y * dt1;
    const float p2  = p1 + sv.z * dt2;
    const float tot = p2 + sv.w * dt3;

    // ---- 32-lane inclusive scan ----
    float scan = tot;
    #pragma unroll
    for (int off = 1; off < 32; off <<= 1) {
        const float v = __shfl_up(scan, off, 32);
        if (seglane >= off) scan += v;
    }
    const float excl = scan - tot;

    // ---- transmittance & weights ----
    const float E0 = __expf(-excl);
    const float e0 = __expf(-(excl + p0));
    const float e1 = __expf(-(excl + p1));
    const float e2 = __expf(-(excl + p2));
    const float e3 = __expf(-scan);
    const float wi0 = E0 - e0;
    const float wi1 = e0 - e1;
    const float wi2 = e1 - e2;
    const float wi3 = e2 - e3;

    fvec4 wiv; wiv.x = wi0; wiv.y = wi1; wiv.z = wi2; wiv.w = wi3;
    __builtin_nontemporal_store(wiv, (fvec4*)(out_wi + sbase));

    // ---- weighted color + depth ----
    // sample 4l+0: c0.x c0.y c0.z | 4l+1: c0.w c1.x c1.y
    // sample 4l+2: c1.z c1.w c2.x | 4l+3: c2.y c2.z c2.w
    float r = wi0 * c0.x + wi1 * c0.w + wi2 * c1.z + wi3 * c2.y;
    float g = wi0 * c0.y + wi1 * c1.x + wi2 * c1.w + wi3 * c2.z;
    float b = wi0 * c0.z + wi1 * c1.y + wi2 * c2.x + wi3 * c2.w;
    float d = wi0 * tv.x + wi1 * tv.y + wi2 * tv.z + wi3 * tv.w;

    #pragma unroll
    for (int off = 16; off >= 1; off >>= 1) {
        r += __shfl_xor(r, off, 32);
        g += __shfl_xor(g, off, 32);
        b += __shfl_xor(b, off, 32);
        d += __shfl_xor(d, off, 32);
    }

    if (seglane == 0) {
        out_color[ray * 3 + 0] = r;
        out_color[ray * 3 + 1] = g;
        out_color[ray * 3 + 2] = b;
        out_depth[ray] = d;
    }
}

extern "C" void kernel_launch(void* const* d_in, const int* in_sizes, int n_in,
                              void* d_out, int out_size, void* d_ws, size_t ws_size,
                              hipStream_t stream) {
    const float* t     = (const float*)d_in[0];
    const float* sigma = (const float*)d_in[1];
    const float* color = (const float*)d_in[2];

    float* out = (float*)d_out;
    float* out_color = out;                         // N*3
    float* out_depth = out_color + (long)NRAYS * 3; // N
    float* out_wi    = out_depth + NRAYS;           // N*S
    float* out_t     = out_wi + (long)NRAYS * S;    // N*S

    const int blocks = NRAYS / RAYS_PER_BLOCK;      // 8192
    nerf_fused_kernel<<<blocks, 256, 0, stream>>>(
        t, sigma, color, out_color, out_depth, out_wi, out_t);
}